// Round 1
// baseline (216.388 us; speedup 1.0000x reference)
//
#include <hip/hip_runtime.h>
#include <math.h>

#define DIM 128
#define N_PTS 512
#define K_NEIGH 16
#define POS_HID 64
#define ATTN_HID 512

// ---------------------------------------------------------------------------
// Kernel 1: qkv[b,n,:] = x[b,:,n] @ w_qkv   (x is (B,128,N), w_qkv (128,384))
// grid = B*N blocks, 128 threads. Thread d computes q[d], k[d], v[d].
// ---------------------------------------------------------------------------
__global__ void qkv_kernel(const float* __restrict__ x,
                           const float* __restrict__ w_qkv,
                           float* __restrict__ qkv) {
    int bn = blockIdx.x;               // b*N + n
    int b = bn / N_PTS, n = bn % N_PTS;
    int d = threadIdx.x;               // 0..127
    __shared__ float xr[DIM];
    xr[d] = x[(b * DIM + d) * N_PTS + n];
    __syncthreads();
    float aq = 0.f, ak = 0.f, av = 0.f;
    for (int c = 0; c < DIM; ++c) {
        float xv = xr[c];
        const float* wr = w_qkv + c * 384;
        aq += xv * wr[d];
        ak += xv * wr[128 + d];
        av += xv * wr[256 + d];
    }
    float* o = qkv + bn * 384;
    o[d] = aq; o[128 + d] = ak; o[256 + d] = av;
}

// ---------------------------------------------------------------------------
// Kernel 2: 16 nearest neighbors by squared distance (monotone w/ sqrt dist;
// softmax+sum over k is permutation-invariant so order within top-16 is
// irrelevant — only the set matters). grid = B*N blocks, 64 threads (1 wave).
// ---------------------------------------------------------------------------
__global__ void topk_kernel(const float* __restrict__ pos,
                            int* __restrict__ idxout) {
    int bn = blockIdx.x;
    int b = bn / N_PTS, i = bn % N_PTS;
    int lane = threadIdx.x;            // 0..63
    __shared__ float d2s[N_PTS];
    float px = pos[(b * N_PTS + i) * 3 + 0];
    float py = pos[(b * N_PTS + i) * 3 + 1];
    float pz = pos[(b * N_PTS + i) * 3 + 2];
    for (int j = lane; j < N_PTS; j += 64) {
        float dx = px - pos[(b * N_PTS + j) * 3 + 0];
        float dy = py - pos[(b * N_PTS + j) * 3 + 1];
        float dz = pz - pos[(b * N_PTS + j) * 3 + 2];
        d2s[j] = dx * dx + dy * dy + dz * dz;
    }
    __syncthreads();
    for (int r = 0; r < K_NEIGH; ++r) {
        float best = 1e30f; int bi = N_PTS;
        for (int j = lane; j < N_PTS; j += 64) {
            float v = d2s[j];
            if (v < best) { best = v; bi = j; }   // first (lowest j) wins ties
        }
        for (int off = 32; off > 0; off >>= 1) {
            float ov = __shfl_down(best, off);
            int   oi = __shfl_down(bi, off);
            if (ov < best || (ov == best && oi < bi)) { best = ov; bi = oi; }
        }
        if (lane == 0) {
            idxout[bn * K_NEIGH + r] = bi;
            d2s[bi] = 1e30f;
        }
        __syncthreads();
    }
}

// ---------------------------------------------------------------------------
// Kernel 3: fused per-point: pos-MLP on 16 neighbors, attn-MLP, per-channel
// softmax over k, aggregate. grid = B*N blocks, 256 threads.
// LDS ~60.6 KB (under the 64 KB static limit).
// ---------------------------------------------------------------------------
__global__ __launch_bounds__(256)
void attn_kernel(const float* __restrict__ pos,
                 const float* __restrict__ qkv,
                 const int*   __restrict__ idxin,
                 const float* __restrict__ pw1, const float* __restrict__ pb1,
                 const float* __restrict__ pw2, const float* __restrict__ pb2,
                 const float* __restrict__ aw1, const float* __restrict__ ab1,
                 const float* __restrict__ aw2, const float* __restrict__ ab2,
                 float* __restrict__ out) {
    int bn = blockIdx.x;
    int b = bn / N_PTS, i = bn % N_PTS;
    int tid = threadIdx.x;

    __shared__ float qi[DIM];
    __shared__ float posi[3];
    __shared__ int   nbr[K_NEIGH];
    __shared__ float ph[K_NEIGH][POS_HID];
    __shared__ __align__(16) float hin[K_NEIGH][DIM];
    __shared__ __align__(16) float vg[K_NEIGH][DIM];
    __shared__ __align__(16) float h1[K_NEIGH][ATTN_HID];
    __shared__ float sim[K_NEIGH][DIM];

    if (tid < K_NEIGH) nbr[tid] = idxin[bn * K_NEIGH + tid];
    if (tid < DIM)     qi[tid]  = qkv[bn * 384 + tid];
    if (tid < 3)       posi[tid] = pos[(b * N_PTS + i) * 3 + tid];
    __syncthreads();

    // --- pos MLP hidden: relu(rel_pos @ pos_w1 + pos_b1), 16*64 units ---
    for (int u = tid; u < K_NEIGH * POS_HID; u += 256) {
        int kk = u >> 6, c = u & 63;
        int j = nbr[kk];
        float rx = posi[0] - pos[(b * N_PTS + j) * 3 + 0];
        float ry = posi[1] - pos[(b * N_PTS + j) * 3 + 1];
        float rz = posi[2] - pos[(b * N_PTS + j) * 3 + 2];
        float h = rx * pw1[c] + ry * pw1[64 + c] + rz * pw1[128 + c] + pb1[c];
        ph[kk][c] = fmaxf(h, 0.f);
    }
    __syncthreads();

    // --- pe = hidden @ pos_w2 + pos_b2; hin = q_i - k_j + pe; vg = v_j + pe ---
    for (int u = tid; u < K_NEIGH * DIM; u += 256) {
        int kk = u >> 7, d = u & 127;
        int j = nbr[kk];
        float acc = pb2[d];
        for (int c = 0; c < POS_HID; ++c) acc += ph[kk][c] * pw2[c * DIM + d];
        const float* qkvj = qkv + (b * N_PTS + j) * 384;
        hin[kk][d] = qi[d] - qkvj[128 + d] + acc;
        vg[kk][d]  = qkvj[256 + d] + acc;
    }
    __syncthreads();

    // --- attn layer 1: h1[kk][c] = relu(hin[kk] . aw1[:,c] + ab1[c]) ---
    // register-block over kk: each weight load feeds 16 FMAs; float4 LDS reads.
    for (int cc = 0; cc < 2; ++cc) {
        int c = tid + cc * 256;
        float acc[K_NEIGH];
        float bb = ab1[c];
#pragma unroll
        for (int kk = 0; kk < K_NEIGH; ++kk) acc[kk] = bb;
        for (int d = 0; d < DIM; d += 4) {
            float w0 = aw1[(d + 0) * ATTN_HID + c];
            float w1 = aw1[(d + 1) * ATTN_HID + c];
            float w2 = aw1[(d + 2) * ATTN_HID + c];
            float w3 = aw1[(d + 3) * ATTN_HID + c];
#pragma unroll
            for (int kk = 0; kk < K_NEIGH; ++kk) {
                const float4 h4 = *(const float4*)&hin[kk][d];
                acc[kk] += h4.x * w0 + h4.y * w1 + h4.z * w2 + h4.w * w3;
            }
        }
#pragma unroll
        for (int kk = 0; kk < K_NEIGH; ++kk) h1[kk][c] = fmaxf(acc[kk], 0.f);
    }
    __syncthreads();

    // --- attn layer 2: sim[kk][d] = h1[kk] . aw2[:,d] + ab2[d] ---
    // 256 threads = 128 d-columns x 2 halves of the 512-long c-sum.
    {
        int d = tid & 127;
        int half = tid >> 7;
        float acc[K_NEIGH];
#pragma unroll
        for (int kk = 0; kk < K_NEIGH; ++kk) acc[kk] = 0.f;
        int c0 = half * 256;
        for (int c = c0; c < c0 + 256; c += 4) {
            float w0 = aw2[(c + 0) * DIM + d];
            float w1 = aw2[(c + 1) * DIM + d];
            float w2 = aw2[(c + 2) * DIM + d];
            float w3 = aw2[(c + 3) * DIM + d];
#pragma unroll
            for (int kk = 0; kk < K_NEIGH; ++kk) {
                const float4 h4 = *(const float4*)&h1[kk][c];
                acc[kk] += h4.x * w0 + h4.y * w1 + h4.z * w2 + h4.w * w3;
            }
        }
        if (half == 0) {
#pragma unroll
            for (int kk = 0; kk < K_NEIGH; ++kk) sim[kk][d] = acc[kk] + ab2[d];
        }
        __syncthreads();
        if (half == 1) {
#pragma unroll
            for (int kk = 0; kk < K_NEIGH; ++kk) sim[kk][d] += acc[kk];
        }
        __syncthreads();
    }

    // --- softmax over k (per channel d) + aggregate with vg ---
    if (tid < DIM) {
        int d = tid;
        float m = -1e30f;
#pragma unroll
        for (int kk = 0; kk < K_NEIGH; ++kk) m = fmaxf(m, sim[kk][d]);
        float s = 0.f, a = 0.f;
#pragma unroll
        for (int kk = 0; kk < K_NEIGH; ++kk) {
            float e = __expf(sim[kk][d] - m);
            s += e;
            a += e * vg[kk][d];
        }
        out[(b * DIM + d) * N_PTS + i] = a / s;
    }
}

extern "C" void kernel_launch(void* const* d_in, const int* in_sizes, int n_in,
                              void* d_out, int out_size, void* d_ws, size_t ws_size,
                              hipStream_t stream) {
    const float* x    = (const float*)d_in[0];
    const float* pos  = (const float*)d_in[1];
    const float* wqkv = (const float*)d_in[2];
    const float* pw1  = (const float*)d_in[3];
    const float* pb1  = (const float*)d_in[4];
    const float* pw2  = (const float*)d_in[5];
    const float* pb2  = (const float*)d_in[6];
    const float* aw1  = (const float*)d_in[7];
    const float* ab1  = (const float*)d_in[8];
    const float* aw2  = (const float*)d_in[9];
    const float* ab2  = (const float*)d_in[10];
    float* out = (float*)d_out;

    int B = in_sizes[0] / (DIM * N_PTS);   // = 2
    int nblk = B * N_PTS;                  // 1024

    float* qkv = (float*)d_ws;                       // B*N*384 floats (3 MB)
    int*   idx = (int*)(qkv + (size_t)nblk * 384);   // B*N*16 ints (64 KB)

    qkv_kernel<<<nblk, DIM, 0, stream>>>(x, wqkv, qkv);
    topk_kernel<<<nblk, 64, 0, stream>>>(pos, idx);
    attn_kernel<<<nblk, 256, 0, stream>>>(pos, qkv, idx,
                                          pw1, pb1, pw2, pb2,
                                          aw1, ab1, aw2, ab2, out);
}

// Round 2
// 126.010 us; speedup vs baseline: 1.7172x; 1.7172x over previous
//
#include <hip/hip_runtime.h>
#include <math.h>

#define DIM 128
#define N_PTS 512
#define K_NEIGH 16
#define POS_HID 64
#define ATTN_HID 512

typedef __attribute__((ext_vector_type(8))) short short8;
typedef __attribute__((ext_vector_type(4))) float f32x4;

__device__ __forceinline__ unsigned short f2b(float f) {
    unsigned int u = __builtin_bit_cast(unsigned int, f);
    u += 0x7fffu + ((u >> 16) & 1u);          // RNE
    return (unsigned short)(u >> 16);
}

// ---------------------------------------------------------------------------
// qkv[b,n,:] = x[b,:,n] @ w_qkv   (fp32, unchanged from R1)
// ---------------------------------------------------------------------------
__global__ void qkv_kernel(const float* __restrict__ x,
                           const float* __restrict__ w_qkv,
                           float* __restrict__ qkv) {
    int bn = blockIdx.x;
    int b = bn / N_PTS, n = bn % N_PTS;
    int d = threadIdx.x;
    __shared__ float xr[DIM];
    xr[d] = x[(b * DIM + d) * N_PTS + n];
    __syncthreads();
    float aq = 0.f, ak = 0.f, av = 0.f;
    for (int c = 0; c < DIM; ++c) {
        float xv = xr[c];
        const float* wr = w_qkv + c * 384;
        aq += xv * wr[d];
        ak += xv * wr[128 + d];
        av += xv * wr[256 + d];
    }
    float* o = qkv + bn * 384;
    o[d] = aq; o[128 + d] = ak; o[256 + d] = av;
}

// ---------------------------------------------------------------------------
// top-16 by squared distance (set-equivalent to reference: softmax+sum over k
// is permutation invariant). Unchanged from R1.
// ---------------------------------------------------------------------------
__global__ void topk_kernel(const float* __restrict__ pos,
                            int* __restrict__ idxout) {
    int bn = blockIdx.x;
    int b = bn / N_PTS, i = bn % N_PTS;
    int lane = threadIdx.x;
    __shared__ float d2s[N_PTS];
    float px = pos[(b * N_PTS + i) * 3 + 0];
    float py = pos[(b * N_PTS + i) * 3 + 1];
    float pz = pos[(b * N_PTS + i) * 3 + 2];
    for (int j = lane; j < N_PTS; j += 64) {
        float dx = px - pos[(b * N_PTS + j) * 3 + 0];
        float dy = py - pos[(b * N_PTS + j) * 3 + 1];
        float dz = pz - pos[(b * N_PTS + j) * 3 + 2];
        d2s[j] = dx * dx + dy * dy + dz * dz;
    }
    __syncthreads();
    for (int r = 0; r < K_NEIGH; ++r) {
        float best = 1e30f; int bi = N_PTS;
        for (int j = lane; j < N_PTS; j += 64) {
            float v = d2s[j];
            if (v < best) { best = v; bi = j; }
        }
        for (int off = 32; off > 0; off >>= 1) {
            float ov = __shfl_down(best, off);
            int   oi = __shfl_down(bi, off);
            if (ov < best || (ov == best && oi < bi)) { best = ov; bi = oi; }
        }
        if (lane == 0) {
            idxout[bn * K_NEIGH + r] = bi;
            d2s[bi] = 1e30f;
        }
        __syncthreads();
    }
}

// ---------------------------------------------------------------------------
// Pack aw1/aw2/pw2 (fp32) into bf16 B-fragment order for mfma_16x16x32_bf16:
// B[k][n] lives in lane l = (k/8 % 4)*16 + (n%16), element j = k%8, per
// (K-step, N-tile). packed[((ks*NT + nt)*64 + l)*8 + j].
// ---------------------------------------------------------------------------
__global__ void pack_kernel(const float* __restrict__ aw1,
                            const float* __restrict__ aw2,
                            const float* __restrict__ pw2,
                            unsigned short* __restrict__ p1,
                            unsigned short* __restrict__ p2,
                            unsigned short* __restrict__ p3) {
    int t = blockIdx.x * 256 + threadIdx.x;
    if (t < 65536) {                       // aw1: 128x512, ks 0..3, nt 0..31
        int j = t & 7, l = (t >> 3) & 63, nt = (t >> 9) & 31, ks = t >> 14;
        int k = ks * 32 + (l >> 4) * 8 + j, n = nt * 16 + (l & 15);
        p1[t] = f2b(aw1[k * ATTN_HID + n]);
    } else if (t < 131072) {               // aw2: 512x128, ch 0..15, nt 0..7
        int u = t - 65536;
        int j = u & 7, l = (u >> 3) & 63, nt = (u >> 9) & 7, ch = u >> 12;
        int k = ch * 32 + (l >> 4) * 8 + j, n = nt * 16 + (l & 15);
        p2[u] = f2b(aw2[k * DIM + n]);
    } else if (t < 139264) {               // pw2: 64x128, ks 0..1, nt 0..7
        int u = t - 131072;
        int j = u & 7, l = (u >> 3) & 63, nt = (u >> 9) & 7, ks = u >> 12;
        int k = ks * 32 + (l >> 4) * 8 + j, n = nt * 16 + (l & 15);
        p3[u] = f2b(pw2[k * DIM + n]);
    }
}

// ---------------------------------------------------------------------------
// Fused attention: 4 points/block, 1 point/wave, zero barriers.
// pos-MLP (VALU) -> pe GEMM (MFMA, K=64) -> hin/vg in C-layout (vg in VGPRs)
// -> layer1/layer2 interleaved MFMA chain (h1 round-trips C->A layout through
// per-wave LDS) -> shfl_xor softmax over the 16 neighbors -> store.
// ab2 skipped: softmax over k is invariant to a per-channel constant.
// ---------------------------------------------------------------------------
__global__ __launch_bounds__(256)
void attn_mfma_kernel(const float* __restrict__ pos,
                      const float* __restrict__ qkv,
                      const int*   __restrict__ idxg,
                      const float* __restrict__ pw1,
                      const float* __restrict__ pb1,
                      const float* __restrict__ pb2,
                      const unsigned short* __restrict__ p1,
                      const unsigned short* __restrict__ p2,
                      const unsigned short* __restrict__ p3,
                      const float* __restrict__ ab1,
                      float* __restrict__ out) {
    // A-tiles in LDS, bf16. Strides padded to keep 16B alignment + bank spread.
    __shared__ __align__(16) unsigned short hinA[64][136];   // 17.4 KB
    __shared__ __align__(16) unsigned short phA[64][72];     //  9.2 KB
    __shared__ __align__(16) unsigned short h1s[4][16][40];  //  5.1 KB

    const int tid = threadIdx.x;
    const int w = tid >> 6, lane = tid & 63, quad = lane >> 4, lq = lane & 15;
    const int bn0 = blockIdx.x * 4;

    // ---- stage 1: pos-MLP hidden (relu(rel_pos@pw1+pb1)) -> phA (per-wave rows)
    {
        int row = tid >> 2, cs = (tid & 3) << 4;     // row 0..63, 16 c's each
        int pl = row >> 4, kk = row & 15;
        int g = bn0 + pl, b = g >> 9;
        int j = idxg[g * 16 + kk];
        int ibase = g * 3;
        int jbase = (b * N_PTS + j) * 3;
        float rx = pos[ibase + 0] - pos[jbase + 0];
        float ry = pos[ibase + 1] - pos[jbase + 1];
        float rz = pos[ibase + 2] - pos[jbase + 2];
#pragma unroll 4
        for (int c = cs; c < cs + 16; ++c) {
            float h = rx * pw1[c] + ry * pw1[64 + c] + rz * pw1[128 + c] + pb1[c];
            phA[row][c] = f2b(fmaxf(h, 0.f));
        }
    }

    const int g = bn0 + w, b = g >> 9, n = g & (N_PTS - 1);

    // ---- stage 2: pe = phA @ pw2 + pb2  (MFMA, M=16 K=64 N=128), C-layout regs
    f32x4 pe[8];
    {
        const short8 a0 = *(const short8*)&phA[w * 16 + lq][quad * 8];
        const short8 a1 = *(const short8*)&phA[w * 16 + lq][32 + quad * 8];
#pragma unroll
        for (int nt = 0; nt < 8; ++nt) {
            f32x4 acc = {0.f, 0.f, 0.f, 0.f};
            const short8 b0 = *(const short8*)(p3 + (size_t)((0 * 8 + nt) * 64 + lane) * 8);
            const short8 b1 = *(const short8*)(p3 + (size_t)((1 * 8 + nt) * 64 + lane) * 8);
            acc = __builtin_amdgcn_mfma_f32_16x16x32_bf16(a0, b0, acc, 0, 0, 0);
            acc = __builtin_amdgcn_mfma_f32_16x16x32_bf16(a1, b1, acc, 0, 0, 0);
            float bias = pb2[nt * 16 + lq];
#pragma unroll
            for (int r = 0; r < 4; ++r) pe[nt][r] = acc[r] + bias;
        }
    }

    // ---- stage 3: hin = q_i - k_j + pe (bf16 -> hinA), vg = v_j + pe (VGPRs)
    f32x4 vg[8];
    {
        int jr[4];
#pragma unroll
        for (int r = 0; r < 4; ++r) jr[r] = idxg[g * 16 + quad * 4 + r];
#pragma unroll
        for (int nt = 0; nt < 8; ++nt) {
            int d = nt * 16 + lq;
            float qv = qkv[g * 384 + d];
#pragma unroll
            for (int r = 0; r < 4; ++r) {
                const float* kv = qkv + (size_t)(b * N_PTS + jr[r]) * 384;
                float p = pe[nt][r];
                float hv = qv - kv[128 + d] + p;
                vg[nt][r] = kv[256 + d] + p;
                hinA[w * 16 + quad * 4 + r][d] = f2b(hv);
            }
        }
    }

    // ---- stage 4: layer1 (16x128 @ 128x512) + layer2 (16x512 @ 512x128),
    // interleaved in 32-col chunks; h1 C->A layout via per-wave LDS.
    short8 a1f[4];
#pragma unroll
    for (int ks = 0; ks < 4; ++ks)
        a1f[ks] = *(const short8*)&hinA[w * 16 + lq][ks * 32 + quad * 8];

    f32x4 c2[8];
#pragma unroll
    for (int nt = 0; nt < 8; ++nt) c2[nt] = (f32x4){0.f, 0.f, 0.f, 0.f};

    for (int ch = 0; ch < 16; ++ch) {
#pragma unroll
        for (int t = 0; t < 2; ++t) {
            int nt = ch * 2 + t;
            f32x4 acc = {0.f, 0.f, 0.f, 0.f};
#pragma unroll
            for (int ks = 0; ks < 4; ++ks) {
                const short8 bf = *(const short8*)(p1 + (size_t)(((ks << 5) + nt) * 64 + lane) * 8);
                acc = __builtin_amdgcn_mfma_f32_16x16x32_bf16(a1f[ks], bf, acc, 0, 0, 0);
            }
            float bias = ab1[nt * 16 + lq];
#pragma unroll
            for (int r = 0; r < 4; ++r)
                h1s[w][quad * 4 + r][t * 16 + lq] = f2b(fmaxf(acc[r] + bias, 0.f));
        }
        const short8 a2 = *(const short8*)&h1s[w][lq][quad * 8];
#pragma unroll
        for (int nt2 = 0; nt2 < 8; ++nt2) {
            const short8 bf = *(const short8*)(p2 + (size_t)(((ch << 3) + nt2) * 64 + lane) * 8);
            c2[nt2] = __builtin_amdgcn_mfma_f32_16x16x32_bf16(a2, bf, c2[nt2], 0, 0, 0);
        }
    }

    // ---- stage 5: softmax over the 16 neighbors (4 regs x 4 quads) + store
#pragma unroll
    for (int nt2 = 0; nt2 < 8; ++nt2) {
        f32x4 s4 = c2[nt2];
        float m = fmaxf(fmaxf(s4[0], s4[1]), fmaxf(s4[2], s4[3]));
        m = fmaxf(m, __shfl_xor(m, 16));
        m = fmaxf(m, __shfl_xor(m, 32));
        float e0 = __expf(s4[0] - m), e1 = __expf(s4[1] - m);
        float e2 = __expf(s4[2] - m), e3 = __expf(s4[3] - m);
        float s = e0 + e1 + e2 + e3;
        f32x4 v4 = vg[nt2];
        float a = e0 * v4[0] + e1 * v4[1] + e2 * v4[2] + e3 * v4[3];
        s += __shfl_xor(s, 16); s += __shfl_xor(s, 32);
        a += __shfl_xor(a, 16); a += __shfl_xor(a, 32);
        if (quad == 0)
            out[(size_t)(b * DIM + nt2 * 16 + lq) * N_PTS + n] = a / s;
    }
}

extern "C" void kernel_launch(void* const* d_in, const int* in_sizes, int n_in,
                              void* d_out, int out_size, void* d_ws, size_t ws_size,
                              hipStream_t stream) {
    const float* x    = (const float*)d_in[0];
    const float* pos  = (const float*)d_in[1];
    const float* wqkv = (const float*)d_in[2];
    const float* pw1  = (const float*)d_in[3];
    const float* pb1  = (const float*)d_in[4];
    const float* pw2  = (const float*)d_in[5];
    const float* pb2  = (const float*)d_in[6];
    const float* aw1  = (const float*)d_in[7];
    const float* ab1  = (const float*)d_in[8];
    const float* aw2  = (const float*)d_in[9];
    // ab2 (d_in[10]) unused: softmax over k is invariant to per-channel bias.
    float* out = (float*)d_out;

    int B = in_sizes[0] / (DIM * N_PTS);
    int npts = B * N_PTS;                    // 1024

    char* ws = (char*)d_ws;
    float* qkv = (float*)ws;                                   // npts*384 f32
    int*   idx = (int*)(ws + (size_t)npts * 384 * 4);          // npts*16 int
    unsigned short* p1 = (unsigned short*)(ws + (size_t)npts * 384 * 4 + (size_t)npts * 16 * 4);
    unsigned short* p2 = p1 + 65536;
    unsigned short* p3 = p2 + 65536;

    pack_kernel<<<545, 256, 0, stream>>>(aw1, aw2, pw2, p1, p2, p3);
    qkv_kernel<<<npts, DIM, 0, stream>>>(x, wqkv, qkv);
    topk_kernel<<<npts, 64, 0, stream>>>(pos, idx);
    attn_mfma_kernel<<<npts / 4, 256, 0, stream>>>(pos, qkv, idx,
                                                   pw1, pb1, pb2,
                                                   p1, p2, p3, ab1, out);
}